// Round 1
// 318.883 us; speedup vs baseline: 1.0042x; 1.0042x over previous
//
#include <hip/hip_runtime.h>

typedef __bf16 bf16_t;
typedef __bf16 bf16x8 __attribute__((ext_vector_type(8)));
typedef __bf16 bf16x4 __attribute__((ext_vector_type(4)));
typedef __bf16 bf16x2 __attribute__((ext_vector_type(2)));
typedef float  f32x4  __attribute__((ext_vector_type(4)));
typedef float  f32x16 __attribute__((ext_vector_type(16)));
typedef unsigned int u32x4 __attribute__((ext_vector_type(4)));
typedef int i32x2 __attribute__((ext_vector_type(2)));

#define MFMA16(A, B, C) __builtin_amdgcn_mfma_f32_16x16x32_bf16((A), (B), (C), 0, 0, 0)
#define MFMA32(A, B, C) __builtin_amdgcn_mfma_f32_32x32x16_bf16((A), (B), (C), 0, 0, 0)

constexpr int BB = 4;
constexpr int SS = 2048;
constexpr int DD = 1024;
constexpr int HH = 16;
constexpr int DH = 64;
// p = exp2(score * SCALE * log2(e) - vml*log2(e)); SCALE = 1/8
constexpr float C1 = 0.18033688011112042f;  // 0.125 * log2(e)

// async global->LDS, 16B per lane. LDS dest = wave-uniform base + lane*16.
__device__ __forceinline__ void async_copy16(const void* g, void* l) {
    __builtin_amdgcn_global_load_lds(
        (const __attribute__((address_space(1))) void*)g,
        (__attribute__((address_space(3))) void*)l, 16, 0, 0);
}

// pack two f32 into one u32 of 2 bf16 (compiler emits v_cvt_pk; m240: faster
// than hand-written inline asm)
__device__ __forceinline__ unsigned pack_bf16(float lo, float hi) {
    bf16x2 t;
    t[0] = (bf16_t)lo;
    t[1] = (bf16_t)hi;
    return __builtin_bit_cast(unsigned, t);
}

// v_permlane32_swap_b32: a = {a.lo32, b.lo32}, b = {a.hi32, b.hi32}
__device__ __forceinline__ void permswap(unsigned& a, unsigned& b) {
    i32x2 r = __builtin_amdgcn_permlane32_swap((int)a, (int)b, false, false);
    a = (unsigned)r[0];
    b = (unsigned)r[1];
}

// ---------------------------------------------------------------------------
// fp32 -> bf16 conversion of q,k,v inputs. grid (4096,1,3), block 256.
// ---------------------------------------------------------------------------
__global__ __launch_bounds__(256) void conv_kernel(
    const float* __restrict__ q, const float* __restrict__ k,
    const float* __restrict__ v, bf16_t* __restrict__ outb)
{
    const float* src = blockIdx.z == 0 ? q : blockIdx.z == 1 ? k : v;
    bf16_t* dst = outb + ((size_t)blockIdx.z << 23);
    size_t i = ((size_t)blockIdx.x * 256 + threadIdx.x) * 8;
    f32x4 a = *(const f32x4*)&src[i];
    f32x4 b = *(const f32x4*)&src[i + 4];
    bf16x8 o;
    o[0] = (bf16_t)a[0]; o[1] = (bf16_t)a[1]; o[2] = (bf16_t)a[2]; o[3] = (bf16_t)a[3];
    o[4] = (bf16_t)b[0]; o[5] = (bf16_t)b[1]; o[6] = (bf16_t)b[2]; o[7] = (bf16_t)b[3];
    *(bf16x8*)&dst[i] = o;
}

// ---------------------------------------------------------------------------
// transpose + convert weights: W[k][n] fp32 -> Wt[n][k] bf16. grid (16,16,3).
// ---------------------------------------------------------------------------
__global__ __launch_bounds__(256) void wtrans_kernel(
    const float* __restrict__ Wq, const float* __restrict__ Wk,
    const float* __restrict__ Wv, bf16_t* __restrict__ Wt)
{
    const float* W = blockIdx.z == 0 ? Wq : blockIdx.z == 1 ? Wk : Wv;
    bf16_t* T = Wt + ((size_t)blockIdx.z << 20);

    __shared__ __align__(16) bf16_t tile[64][72];

    const int k0 = blockIdx.x * 64;
    const int n0 = blockIdx.y * 64;
    const int tid = threadIdx.x;

    #pragma unroll
    for (int i = 0; i < 4; i++) {
        int idx = tid + i * 256;
        int kk = idx >> 4;
        int nn = (idx & 15) * 4;
        f32x4 w = *(const f32x4*)&W[(size_t)(k0 + kk) * 1024 + n0 + nn];
        tile[nn + 0][kk] = (bf16_t)w[0];
        tile[nn + 1][kk] = (bf16_t)w[1];
        tile[nn + 2][kk] = (bf16_t)w[2];
        tile[nn + 3][kk] = (bf16_t)w[3];
    }
    __syncthreads();
    #pragma unroll
    for (int i = 0; i < 2; i++) {
        int idx = tid + i * 256;
        int nn = idx >> 3;
        int kk = (idx & 7) * 8;
        *(bf16x8*)&T[(size_t)(n0 + nn) * 1024 + k0 + kk] =
            *(const bf16x8*)&tile[nn][kk];
    }
}

// ---------------------------------------------------------------------------
// projection GEMM: C = Ab(bf16)[8192x1024] @ Wt^T -> bf16. BK=64.
// XCD swizzle: each XCD gets a contiguous 8-m-panel stripe x all n-tiles,
// so A is fetched once device-wide and only B (2 MB) duplicates per XCD.
// grid (512, 1, 3), block 256: 4 waves, each 64x64 of the 128x128 tile.
// ---------------------------------------------------------------------------
__global__ __launch_bounds__(256) void proj_kernel(
    const bf16_t* __restrict__ Ab, const bf16_t* __restrict__ Wt,
    bf16_t* __restrict__ qw, bf16_t* __restrict__ kw, bf16_t* __restrict__ vwt)
{
    const int which = blockIdx.z;
    const bf16_t* A = Ab + ((size_t)which << 23);
    const bf16_t* T = Wt + ((size_t)which << 20);

    __shared__ bf16_t Alds[128 * 64];  // [row][64k], 16B chunk c at c^(row&7)
    __shared__ bf16_t Blds[128 * 64];

    const int tid = threadIdx.x;
    const int lane = tid & 63;
    const int wave = tid >> 6;
    const int quad = lane >> 4;
    const int l16 = lane & 15;

    // XCD-locality decode: presumed placement XCD = blockIdx.x % 8
    const int id = blockIdx.x;
    const int xg = id & 7;
    const int sl = id >> 3;                   // 0..63
    const int m0 = (((xg << 3) | (sl >> 3))) * 128;  // XCD xg: m-panels xg*8..xg*8+7
    const int n0 = (sl & 7) * 128;

    const int wm = (wave >> 1) * 64;
    const int wn = (wave & 1) * 64;

    const int srow = lane >> 3;   // 8 rows per staging instr
    const int schk = lane & 7;    // physical 16B chunk

    f32x4 zero4 = {0.f, 0.f, 0.f, 0.f};
    f32x4 acc[4][4];
    #pragma unroll
    for (int i = 0; i < 4; i++)
        #pragma unroll
        for (int j = 0; j < 4; j++) acc[i][j] = zero4;

    for (int k0 = 0; k0 < DD; k0 += 64) {
        #pragma unroll
        for (int j = 0; j < 4; j++) {
            int r0 = wave * 32 + j * 8;
            int row = r0 + srow;
            int c = schk ^ (row & 7);
            async_copy16(&A[(size_t)(m0 + row) * 1024 + k0 + c * 8], &Alds[r0 * 64]);
        }
        #pragma unroll
        for (int j = 0; j < 4; j++) {
            int r0 = wave * 32 + j * 8;
            int row = r0 + srow;
            int c = schk ^ (row & 7);
            async_copy16(&T[(size_t)(n0 + row) * 1024 + k0 + c * 8], &Blds[r0 * 64]);
        }
        __syncthreads();

        #pragma unroll
        for (int s = 0; s < 2; s++) {
            bf16x8 af[4], bfr[4];
            #pragma unroll
            for (int mi = 0; mi < 4; mi++)
                af[mi] = *(const bf16x8*)&Alds[(wm + mi * 16 + l16) * 64 +
                             (((s * 4 + quad) ^ (l16 & 7)) << 3)];
            #pragma unroll
            for (int ni = 0; ni < 4; ni++)
                bfr[ni] = *(const bf16x8*)&Blds[(wn + ni * 16 + l16) * 64 +
                              (((s * 4 + quad) ^ (l16 & 7)) << 3)];
            #pragma unroll
            for (int mi = 0; mi < 4; mi++)
                #pragma unroll
                for (int ni = 0; ni < 4; ni++)
                    acc[mi][ni] = MFMA16(af[mi], bfr[ni], acc[mi][ni]);
        }
        __syncthreads();
    }

    // C/D layout: col=lane&15, row=quad*4+reg
    if (which < 2) {
        bf16_t* Cout = which == 0 ? qw : kw;
        #pragma unroll
        for (int mi = 0; mi < 4; mi++)
            #pragma unroll
            for (int ni = 0; ni < 4; ni++)
                #pragma unroll
                for (int r = 0; r < 4; r++) {
                    int row = m0 + wm + mi * 16 + quad * 4 + r;
                    int col = n0 + wn + ni * 16 + l16;
                    Cout[(size_t)row * 1024 + col] = (bf16_t)acc[mi][ni][r];
                }
    } else {
        // vwt[b][h][d][s]; the 4 acc regs are s-consecutive -> bf16x4 stores
        #pragma unroll
        for (int mi = 0; mi < 4; mi++)
            #pragma unroll
            for (int ni = 0; ni < 4; ni++) {
                int s0 = m0 + wm + mi * 16 + quad * 4;
                int col = n0 + wn + ni * 16 + l16;
                int b = s0 >> 11, s = s0 & 2047;
                int h = col >> 6, d = col & 63;
                bf16x4 p;
                p[0] = (bf16_t)acc[mi][ni][0]; p[1] = (bf16_t)acc[mi][ni][1];
                p[2] = (bf16_t)acc[mi][ni][2]; p[3] = (bf16_t)acc[mi][ni][3];
                *(bf16x4*)&vwt[(((size_t)((b * HH + h) * DH + d)) << 11) + s] = p;
            }
    }
}

// ---------------------------------------------------------------------------
// flash attention, 32x32 swapped-operand form, no-rescale softmax.
// S^T = MFMA32(K, Q): each lane holds a full 32-key P column slice for one
// query (col = lane&31), so P never touches LDS: pack to bf16 pairs +
// permlane32_swap builds the PV B-operand entirely in registers (T12).
// KVBLK=64, double-buffered K/V staging (T14): stage(next) issued before
// compute(cur), single barrier per tile.
// XCD swizzle: all 16 q-tiles of one (b,h) group share linear%8 -> one L2.
// grid (1024, 1, 1), block 256 (4 waves x 32 queries).
// ---------------------------------------------------------------------------
__global__ __launch_bounds__(256) void attn_kernel(
    const bf16_t* __restrict__ qw, const bf16_t* __restrict__ kw,
    const bf16_t* __restrict__ vwt, const float* __restrict__ v_mask,
    const float* __restrict__ q_mask, float* __restrict__ out)
{
    // XCD-locality decode
    const int linear = blockIdx.x;           // 0..1023
    const int xg = linear & 7;               // presumed XCD
    const int sl = linear >> 3;              // 0..127
    const int grp = (xg << 3) | (sl >> 4);   // 0..63: XCD xg gets groups xg*8..+7
    const int qt = sl & 15;
    const int b = grp >> 4;
    const int h = grp & 15;

    __shared__ __align__(16) bf16_t Klds[2][64 * 64];   // [key][d], chunk^(key&7)
    __shared__ __align__(16) bf16_t Vtlds[2][64 * 64];  // [d][key], chunk^(d&7)
    __shared__ float vml[2][64];             // (1-v_mask)*1e10*log2e

    const int tid = threadIdx.x;
    const int lane = tid & 63;
    const int wave = tid >> 6;
    const int l5 = lane & 31;
    const int hi = lane >> 5;
    const int q0 = qt * 128 + wave * 32;

    const int srow = lane >> 3;   // staging: 8 rows per instr
    const int schk = lane & 7;    // physical 16B chunk

    // Q fragments: B-operand, lane holds col=query(l5), k = d = c*16+hi*8..+7
    bf16x8 qf[4];
    #pragma unroll
    for (int c = 0; c < 4; ++c)
        qf[c] = *(const bf16x8*)&qw[(size_t)(b * SS + q0 + l5) * 1024 + h * 64 +
                                    c * 16 + hi * 8];

    f32x16 zero16;
    #pragma unroll
    for (int i = 0; i < 16; ++i) zero16[i] = 0.f;

    auto stage = [&](int bi, int kt) {
        #pragma unroll
        for (int j = 0; j < 2; ++j) {
            int r0 = (wave * 2 + j) * 8;
            int row = r0 + srow;
            int c = schk ^ (row & 7);
            async_copy16(&kw[(size_t)(b * SS + kt + row) * 1024 + h * 64 + c * 8],
                         &Klds[bi][r0 * 64]);
        }
        #pragma unroll
        for (int j = 0; j < 2; ++j) {
            int r0 = (wave * 2 + j) * 8;
            int d = r0 + srow;
            int c = schk ^ (d & 7);
            async_copy16(&vwt[(((size_t)((b * HH + h) * DH + d)) << 11) + kt + c * 8],
                         &Vtlds[bi][r0 * 64]);
        }
        if (tid < 64)
            vml[bi][tid] = (1.0f - v_mask[b * SS + kt + tid]) * 1.4426950408889634e10f;
    };

    stage(0, 0);
    __syncthreads();

    f32x16 o0 = zero16, o1 = zero16;   // O^T: rows d 0-31 / 32-63, col = query
    f32x4 l4 = {0.f, 0.f, 0.f, 0.f};   // 4 independent l-sum chains

    for (int t = 0; t < 32; ++t) {
        const int cur = t & 1;
        if (t < 31) stage(cur ^ 1, (t + 1) * 64);   // prefetch while computing

        // S^T = K @ Q^T: row = key, col = query(l5). Two 32-key blocks.
        f32x16 st0 = zero16, st1 = zero16;
        #pragma unroll
        for (int c = 0; c < 4; ++c) {
            const int sw = ((c * 2 + hi) ^ (l5 & 7)) << 3;
            bf16x8 k0 = *(const bf16x8*)&Klds[cur][l5 * 64 + sw];
            bf16x8 k1 = *(const bf16x8*)&Klds[cur][(32 + l5) * 64 + sw];
            st0 = MFMA32(k0, qf[c], st0);
            st1 = MFMA32(k1, qf[c], st1);
        }

        #pragma unroll
        for (int kb = 0; kb < 2; ++kb) {
            f32x16 st = kb ? st1 : st0;
            // softmax (no max, no rescale): p = exp2(s*C1 - vml[key])
            // key(reg r) = kb*32 + (r&3) + 8*(r>>2) + 4*hi
            #pragma unroll
            for (int g = 0; g < 4; ++g) {
                f32x4 vm4 = *(const f32x4*)&vml[cur][kb * 32 + g * 8 + hi * 4];
                #pragma unroll
                for (int j = 0; j < 4; ++j) {
                    float p = __builtin_amdgcn_exp2f(
                        __builtin_fmaf(st[g * 4 + j], C1, -vm4[j]));
                    st[g * 4 + j] = p;
                    l4[j] += p;
                }
            }
            // pack P pairs and swap halves: B-operand word w holds keys
            // hi*8+2w, hi*8+2w+1 of its 16-key chunk (T12 pairing)
            unsigned a0 = pack_bf16(st[0],  st[1]);
            unsigned a1 = pack_bf16(st[2],  st[3]);
            unsigned a2 = pack_bf16(st[4],  st[5]);
            unsigned a3 = pack_bf16(st[6],  st[7]);
            unsigned a4 = pack_bf16(st[8],  st[9]);
            unsigned a5 = pack_bf16(st[10], st[11]);
            unsigned a6 = pack_bf16(st[12], st[13]);
            unsigned a7 = pack_bf16(st[14], st[15]);
            permswap(a0, a2);
            permswap(a1, a3);
            permswap(a4, a6);
            permswap(a5, a7);
            u32x4 w0 = {a0, a1, a2, a3};   // keys kb*32 + [0,16)
            u32x4 w1 = {a4, a5, a6, a7};   // keys kb*32 + [16,32)
            bf16x8 bp0 = __builtin_bit_cast(bf16x8, w0);
            bf16x8 bp1 = __builtin_bit_cast(bf16x8, w1);

            // O^T += V^T @ P  (A = V^T rows d, k = key chunk of 16)
            #pragma unroll
            for (int c = 0; c < 2; ++c) {
                bf16x8 bp = c ? bp1 : bp0;
                const int sw = (((kb * 4 + c * 2 + hi)) ^ (l5 & 7)) << 3;
                bf16x8 av0 = *(const bf16x8*)&Vtlds[cur][l5 * 64 + sw];
                bf16x8 av1 = *(const bf16x8*)&Vtlds[cur][(32 + l5) * 64 + sw];
                o0 = MFMA32(av0, bp, o0);
                o1 = MFMA32(av1, bp, o1);
            }
        }
        if (t < 31) __syncthreads();   // next buffer staged; cur reads done
    }

    // combine l partials: 4 chains, then the two lane-halves (hi) per query
    float l_i = (l4[0] + l4[1]) + (l4[2] + l4[3]);
    l_i += __shfl_xor(l_i, 32);

    const int q = q0 + l5;
    const float sc = q_mask[b * SS + q] / l_i;
    // O^T reg r: d = db*32 + (r&3) + 8*(r>>2) + 4*hi, col q = l5
    #pragma unroll
    for (int db = 0; db < 2; ++db) {
        const f32x16 oa = db ? o1 : o0;
        #pragma unroll
        for (int g = 0; g < 4; ++g) {
            f32x4 o4;
            o4[0] = oa[g * 4 + 0] * sc;
            o4[1] = oa[g * 4 + 1] * sc;
            o4[2] = oa[g * 4 + 2] * sc;
            o4[3] = oa[g * 4 + 3] * sc;
            *(f32x4*)&out[(size_t)(b * SS + q) * 1024 + h * 64 +
                          db * 32 + g * 8 + hi * 4] = o4;
        }
    }
}

// ---------------------------------------------------------------------------
extern "C" void kernel_launch(void* const* d_in, const int* in_sizes, int n_in,
                              void* d_out, int out_size, void* d_ws, size_t ws_size,
                              hipStream_t stream)
{
    const float* q  = (const float*)d_in[0];
    const float* k  = (const float*)d_in[1];
    const float* v  = (const float*)d_in[2];
    const float* vm = (const float*)d_in[3];
    const float* qm = (const float*)d_in[4];
    const float* Wq = (const float*)d_in[5];
    const float* Wk = (const float*)d_in[6];
    const float* Wv = (const float*)d_in[7];
    float* out = (float*)d_out;

    const size_t elems = (size_t)BB * SS * DD;  // 8388608
    bf16_t* Ab  = (bf16_t*)d_ws;       // qb,kb,vb: 3*elems
    bf16_t* qw  = Ab + 3 * elems;
    bf16_t* kw  = qw + elems;
    bf16_t* vwt = kw + elems;
    bf16_t* Wt  = vwt + elems;         // 3 x 1024 x 1024

    conv_kernel<<<dim3(4096, 1, 3), 256, 0, stream>>>(q, k, v, Ab);
    wtrans_kernel<<<dim3(16, 16, 3), 256, 0, stream>>>(Wq, Wk, Wv, Wt);
    proj_kernel<<<dim3(512, 1, 3), 256, 0, stream>>>(Ab, Wt, qw, kw, vwt);
    attn_kernel<<<dim3(1024, 1, 1), 256, 0, stream>>>(qw, kw, vwt, vm, qm, out);
}

// Round 2
// 316.984 us; speedup vs baseline: 1.0102x; 1.0060x over previous
//
#include <hip/hip_runtime.h>

typedef __bf16 bf16_t;
typedef __bf16 bf16x8 __attribute__((ext_vector_type(8)));
typedef __bf16 bf16x4 __attribute__((ext_vector_type(4)));
typedef __bf16 bf16x2 __attribute__((ext_vector_type(2)));
typedef float  f32x4  __attribute__((ext_vector_type(4)));
typedef float  f32x16 __attribute__((ext_vector_type(16)));
typedef unsigned int u32x4 __attribute__((ext_vector_type(4)));
typedef int i32x2 __attribute__((ext_vector_type(2)));

#define MFMA16(A, B, C) __builtin_amdgcn_mfma_f32_16x16x32_bf16((A), (B), (C), 0, 0, 0)
#define MFMA32(A, B, C) __builtin_amdgcn_mfma_f32_32x32x16_bf16((A), (B), (C), 0, 0, 0)

constexpr int BB = 4;
constexpr int SS = 2048;
constexpr int DD = 1024;
constexpr int HH = 16;
constexpr int DH = 64;
// p = exp2(score * SCALE * log2(e) - vml*log2(e)); SCALE = 1/8
constexpr float C1 = 0.18033688011112042f;  // 0.125 * log2(e)

// async global->LDS, 16B per lane. LDS dest = wave-uniform base + lane*16.
__device__ __forceinline__ void async_copy16(const void* g, void* l) {
    __builtin_amdgcn_global_load_lds(
        (const __attribute__((address_space(1))) void*)g,
        (__attribute__((address_space(3))) void*)l, 16, 0, 0);
}

// pack two f32 into one u32 of 2 bf16 (compiler emits v_cvt_pk)
__device__ __forceinline__ unsigned pack_bf16(float lo, float hi) {
    bf16x2 t;
    t[0] = (bf16_t)lo;
    t[1] = (bf16_t)hi;
    return __builtin_bit_cast(unsigned, t);
}

// v_permlane32_swap_b32: a = {a.lo32, b.lo32}, b = {a.hi32, b.hi32}
__device__ __forceinline__ void permswap(unsigned& a, unsigned& b) {
    i32x2 r = __builtin_amdgcn_permlane32_swap((int)a, (int)b, false, false);
    a = (unsigned)r[0];
    b = (unsigned)r[1];
}

// ---------------------------------------------------------------------------
// fp32 -> bf16 conversion of q,k,v inputs. grid (4096,1,3), block 256.
// ---------------------------------------------------------------------------
__global__ __launch_bounds__(256) void conv_kernel(
    const float* __restrict__ q, const float* __restrict__ k,
    const float* __restrict__ v, bf16_t* __restrict__ outb)
{
    const float* src = blockIdx.z == 0 ? q : blockIdx.z == 1 ? k : v;
    bf16_t* dst = outb + ((size_t)blockIdx.z << 23);
    size_t i = ((size_t)blockIdx.x * 256 + threadIdx.x) * 8;
    f32x4 a = *(const f32x4*)&src[i];
    f32x4 b = *(const f32x4*)&src[i + 4];
    bf16x8 o;
    o[0] = (bf16_t)a[0]; o[1] = (bf16_t)a[1]; o[2] = (bf16_t)a[2]; o[3] = (bf16_t)a[3];
    o[4] = (bf16_t)b[0]; o[5] = (bf16_t)b[1]; o[6] = (bf16_t)b[2]; o[7] = (bf16_t)b[3];
    *(bf16x8*)&dst[i] = o;
}

// ---------------------------------------------------------------------------
// transpose + convert weights: W[k][n] fp32 -> Wt[n][k] bf16. grid (16,16,3).
// ---------------------------------------------------------------------------
__global__ __launch_bounds__(256) void wtrans_kernel(
    const float* __restrict__ Wq, const float* __restrict__ Wk,
    const float* __restrict__ Wv, bf16_t* __restrict__ Wt)
{
    const float* W = blockIdx.z == 0 ? Wq : blockIdx.z == 1 ? Wk : Wv;
    bf16_t* T = Wt + ((size_t)blockIdx.z << 20);

    __shared__ __align__(16) bf16_t tile[64][72];

    const int k0 = blockIdx.x * 64;
    const int n0 = blockIdx.y * 64;
    const int tid = threadIdx.x;

    #pragma unroll
    for (int i = 0; i < 4; i++) {
        int idx = tid + i * 256;
        int kk = idx >> 4;
        int nn = (idx & 15) * 4;
        f32x4 w = *(const f32x4*)&W[(size_t)(k0 + kk) * 1024 + n0 + nn];
        tile[nn + 0][kk] = (bf16_t)w[0];
        tile[nn + 1][kk] = (bf16_t)w[1];
        tile[nn + 2][kk] = (bf16_t)w[2];
        tile[nn + 3][kk] = (bf16_t)w[3];
    }
    __syncthreads();
    #pragma unroll
    for (int i = 0; i < 2; i++) {
        int idx = tid + i * 256;
        int nn = idx >> 3;
        int kk = (idx & 7) * 8;
        *(bf16x8*)&T[(size_t)(n0 + nn) * 1024 + k0 + kk] =
            *(const bf16x8*)&tile[nn][kk];
    }
}

// ---------------------------------------------------------------------------
// projection GEMM: C = Ab(bf16)[8192x1024] @ Wt^T -> bf16. BK=64.
// grid (512, 1, 3), block 256: 4 waves, each 64x64 of the 128x128 tile.
// ---------------------------------------------------------------------------
__global__ __launch_bounds__(256) void proj_kernel(
    const bf16_t* __restrict__ Ab, const bf16_t* __restrict__ Wt,
    bf16_t* __restrict__ qw, bf16_t* __restrict__ kw, bf16_t* __restrict__ vwt)
{
    const int which = blockIdx.z;
    const bf16_t* A = Ab + ((size_t)which << 23);
    const bf16_t* T = Wt + ((size_t)which << 20);

    __shared__ bf16_t Alds[128 * 64];  // [row][64k], 16B chunk c at c^(row&7)
    __shared__ bf16_t Blds[128 * 64];

    const int tid = threadIdx.x;
    const int lane = tid & 63;
    const int wave = tid >> 6;
    const int quad = lane >> 4;
    const int l16 = lane & 15;

    // XCD-locality decode: presumed placement XCD = blockIdx.x % 8
    const int id = blockIdx.x;
    const int xg = id & 7;
    const int sl = id >> 3;                   // 0..63
    const int m0 = (((xg << 3) | (sl >> 3))) * 128;  // XCD xg: m-panels xg*8..xg*8+7
    const int n0 = (sl & 7) * 128;

    const int wm = (wave >> 1) * 64;
    const int wn = (wave & 1) * 64;

    const int srow = lane >> 3;   // 8 rows per staging instr
    const int schk = lane & 7;    // physical 16B chunk

    f32x4 zero4 = {0.f, 0.f, 0.f, 0.f};
    f32x4 acc[4][4];
    #pragma unroll
    for (int i = 0; i < 4; i++)
        #pragma unroll
        for (int j = 0; j < 4; j++) acc[i][j] = zero4;

    for (int k0 = 0; k0 < DD; k0 += 64) {
        #pragma unroll
        for (int j = 0; j < 4; j++) {
            int r0 = wave * 32 + j * 8;
            int row = r0 + srow;
            int c = schk ^ (row & 7);
            async_copy16(&A[(size_t)(m0 + row) * 1024 + k0 + c * 8], &Alds[r0 * 64]);
        }
        #pragma unroll
        for (int j = 0; j < 4; j++) {
            int r0 = wave * 32 + j * 8;
            int row = r0 + srow;
            int c = schk ^ (row & 7);
            async_copy16(&T[(size_t)(n0 + row) * 1024 + k0 + c * 8], &Blds[r0 * 64]);
        }
        __syncthreads();

        #pragma unroll
        for (int s = 0; s < 2; s++) {
            bf16x8 af[4], bfr[4];
            #pragma unroll
            for (int mi = 0; mi < 4; mi++)
                af[mi] = *(const bf16x8*)&Alds[(wm + mi * 16 + l16) * 64 +
                             (((s * 4 + quad) ^ (l16 & 7)) << 3)];
            #pragma unroll
            for (int ni = 0; ni < 4; ni++)
                bfr[ni] = *(const bf16x8*)&Blds[(wn + ni * 16 + l16) * 64 +
                              (((s * 4 + quad) ^ (l16 & 7)) << 3)];
            #pragma unroll
            for (int mi = 0; mi < 4; mi++)
                #pragma unroll
                for (int ni = 0; ni < 4; ni++)
                    acc[mi][ni] = MFMA16(af[mi], bfr[ni], acc[mi][ni]);
        }
        __syncthreads();
    }

    // C/D layout: col=lane&15, row=quad*4+reg
    if (which < 2) {
        bf16_t* Cout = which == 0 ? qw : kw;
        #pragma unroll
        for (int mi = 0; mi < 4; mi++)
            #pragma unroll
            for (int ni = 0; ni < 4; ni++)
                #pragma unroll
                for (int r = 0; r < 4; r++) {
                    int row = m0 + wm + mi * 16 + quad * 4 + r;
                    int col = n0 + wn + ni * 16 + l16;
                    Cout[(size_t)row * 1024 + col] = (bf16_t)acc[mi][ni][r];
                }
    } else {
        // vwt[b][h][d][s]; the 4 acc regs are s-consecutive -> bf16x4 stores
        #pragma unroll
        for (int mi = 0; mi < 4; mi++)
            #pragma unroll
            for (int ni = 0; ni < 4; ni++) {
                int s0 = m0 + wm + mi * 16 + quad * 4;
                int col = n0 + wn + ni * 16 + l16;
                int b = s0 >> 11, s = s0 & 2047;
                int h = col >> 6, d = col & 63;
                bf16x4 p;
                p[0] = (bf16_t)acc[mi][ni][0]; p[1] = (bf16_t)acc[mi][ni][1];
                p[2] = (bf16_t)acc[mi][ni][2]; p[3] = (bf16_t)acc[mi][ni][3];
                *(bf16x4*)&vwt[(((size_t)((b * HH + h) * DH + d)) << 11) + s] = p;
            }
    }
}

// ---------------------------------------------------------------------------
// flash attention, 32x32 swapped-operand form, no-rescale softmax.
// Round-2 restructure: the round-1 kernel was VALU-issue-bound (~620
// instrs/wave/tile vs ~120 of softmax math) on per-tile address recompute.
// Now all LDS read addresses are 4 loop-invariant per-lane pointers
// (pj[j] = base + l5*64 + (((l5&7)^hi)^2j)*8, serving BOTH the K reads
// (j=c) and the V reads (j=kb*2+c)) with buffer/half/K-vs-V selection as
// compile-time ds_read offset immediates (t-loop unrolled by 2 so cur is
// constant). Staging uses 4 persistent global pointers += const stride.
// First MFMA of each chain takes zero16 as C directly (no per-tile init
// movs). s_setprio(1) around MFMA clusters (T5).
// grid (1024, 1, 1), block 256 (4 waves x 32 queries).
// ---------------------------------------------------------------------------
__global__ __launch_bounds__(256) void attn_kernel(
    const bf16_t* __restrict__ qw, const bf16_t* __restrict__ kw,
    const bf16_t* __restrict__ vwt, const float* __restrict__ v_mask,
    const float* __restrict__ q_mask, float* __restrict__ out)
{
    // XCD-locality decode
    const int linear = blockIdx.x;           // 0..1023
    const int xg = linear & 7;               // presumed XCD
    const int sl = linear >> 3;              // 0..127
    const int grp = (xg << 3) | (sl >> 4);   // 0..63: XCD xg gets groups xg*8..+7
    const int qt = sl & 15;
    const int b = grp >> 4;
    const int h = grp & 15;

    // flat KV: K[cur] at cur*4096 el, V[cur] at 8192 + cur*4096 el
    __shared__ __align__(16) bf16_t KV[4 * 4096];
    __shared__ float vml[2][64];             // (1-v_mask)*1e10*log2e

    const int tid = threadIdx.x;
    const int lane = tid & 63;
    const int wave = tid >> 6;
    const int l5 = lane & 31;
    const int hi = lane >> 5;
    const int q0 = qt * 128 + wave * 32;

    const int srow = lane >> 3;   // staging: 8 rows per instr
    const int schk = lane & 7;    // physical 16B chunk

    // Q fragments: B-operand, lane holds col=query(l5), k = d = c*16+hi*8..+7
    bf16x8 qf[4];
    #pragma unroll
    for (int c = 0; c < 4; ++c)
        qf[c] = *(const bf16x8*)&qw[(size_t)(b * SS + q0 + l5) * 1024 + h * 64 +
                                    c * 16 + hi * 8];

    f32x16 zero16;
    #pragma unroll
    for (int i = 0; i < 16; ++i) zero16[i] = 0.f;

    // loop-invariant LDS read pointers: chunk((2j+hi)^(l5&7)) = vkh^2j
    const int vkh = (l5 & 7) ^ hi;
    const bf16_t* pj[4];
    #pragma unroll
    for (int j = 0; j < 4; ++j)
        pj[j] = &KV[l5 * 64 + ((vkh ^ (2 * j)) << 3)];
    const float* vmlp = &vml[0][hi * 4];

    // persistent staging pointers (incremented by const stride per tile)
    const bf16_t* gk[2];
    const bf16_t* gv[2];
    #pragma unroll
    for (int j = 0; j < 2; ++j) {
        int row = (wave * 2 + j) * 8 + srow;
        int ck = schk ^ (row & 7);
        gk[j] = &kw[(size_t)(b * SS + row) * 1024 + h * 64 + ck * 8];
        gv[j] = &vwt[(((size_t)((b * HH + h) * DH + row)) << 11) + ck * 8];
    }
    const float* vmp = v_mask + b * SS + tid;

    auto stage = [&](int bi) {
        #pragma unroll
        for (int j = 0; j < 2; ++j) {
            async_copy16(gk[j], &KV[bi * 4096 + (wave * 2 + j) * 512]);
            gk[j] += 64 * 1024;
        }
        #pragma unroll
        for (int j = 0; j < 2; ++j) {
            async_copy16(gv[j], &KV[8192 + bi * 4096 + (wave * 2 + j) * 512]);
            gv[j] += 64;
        }
        if (tid < 64)
            vml[bi][tid] = (1.0f - *vmp) * 1.4426950408889634e10f;
        vmp += 64;
    };

    stage(0);
    __syncthreads();

    f32x16 o0 = zero16, o1 = zero16;   // O^T: rows d 0-31 / 32-63, col = query
    f32x4 l4 = {0.f, 0.f, 0.f, 0.f};   // 4 independent l-sum chains

    for (int t2 = 0; t2 < 32; t2 += 2) {
        #pragma unroll
        for (int cur = 0; cur < 2; ++cur) {
            if (t2 + cur + 1 < 32) stage(cur ^ 1);   // prefetch next tile

            // S^T = K @ Q^T: row = key, col = query(l5). Two 32-key blocks.
            __builtin_amdgcn_s_setprio(1);
            f32x16 st0, st1;
            {
                bf16x8 k0 = *(const bf16x8*)(pj[0] + cur * 4096);
                bf16x8 k1 = *(const bf16x8*)(pj[0] + cur * 4096 + 2048);
                st0 = MFMA32(k0, qf[0], zero16);
                st1 = MFMA32(k1, qf[0], zero16);
            }
            #pragma unroll
            for (int c = 1; c < 4; ++c) {
                bf16x8 k0 = *(const bf16x8*)(pj[c] + cur * 4096);
                bf16x8 k1 = *(const bf16x8*)(pj[c] + cur * 4096 + 2048);
                st0 = MFMA32(k0, qf[c], st0);
                st1 = MFMA32(k1, qf[c], st1);
            }
            __builtin_amdgcn_s_setprio(0);

            #pragma unroll
            for (int kb = 0; kb < 2; ++kb) {
                f32x16& st = kb ? st1 : st0;
                // softmax (no max, no rescale): p = exp2(s*C1 - vml[key])
                // key(reg r) = kb*32 + (r&3) + 8*(r>>2) + 4*hi
                #pragma unroll
                for (int g = 0; g < 4; ++g) {
                    f32x4 vm4 = *(const f32x4*)(vmlp + cur * 64 + kb * 32 + g * 8);
                    #pragma unroll
                    for (int j = 0; j < 4; ++j) {
                        float p = __builtin_amdgcn_exp2f(
                            __builtin_fmaf(st[g * 4 + j], C1, -vm4[j]));
                        st[g * 4 + j] = p;
                        l4[j] += p;
                    }
                }
                // pack P pairs and swap halves (T12 pairing)
                unsigned a0 = pack_bf16(st[0],  st[1]);
                unsigned a1 = pack_bf16(st[2],  st[3]);
                unsigned a2 = pack_bf16(st[4],  st[5]);
                unsigned a3 = pack_bf16(st[6],  st[7]);
                unsigned a4 = pack_bf16(st[8],  st[9]);
                unsigned a5 = pack_bf16(st[10], st[11]);
                unsigned a6 = pack_bf16(st[12], st[13]);
                unsigned a7 = pack_bf16(st[14], st[15]);
                permswap(a0, a2);
                permswap(a1, a3);
                permswap(a4, a6);
                permswap(a5, a7);
                u32x4 w0 = {a0, a1, a2, a3};   // keys kb*32 + [0,16)
                u32x4 w1 = {a4, a5, a6, a7};   // keys kb*32 + [16,32)
                bf16x8 bp0 = __builtin_bit_cast(bf16x8, w0);
                bf16x8 bp1 = __builtin_bit_cast(bf16x8, w1);

                // O^T += V^T @ P  (A = V^T rows d, k = key chunk of 16)
                __builtin_amdgcn_s_setprio(1);
                #pragma unroll
                for (int c = 0; c < 2; ++c) {
                    bf16x8 bp = c ? bp1 : bp0;
                    const bf16_t* pv = pj[kb * 2 + c] + 8192 + cur * 4096;
                    bf16x8 av0 = *(const bf16x8*)(pv);
                    bf16x8 av1 = *(const bf16x8*)(pv + 2048);
                    o0 = MFMA32(av0, bp, o0);
                    o1 = MFMA32(av1, bp, o1);
                }
                __builtin_amdgcn_s_setprio(0);
            }
            __syncthreads();   // next buffer staged; cur reads done
        }
    }

    // combine l partials: 4 chains, then the two lane-halves (hi) per query
    float l_i = (l4[0] + l4[1]) + (l4[2] + l4[3]);
    l_i += __shfl_xor(l_i, 32);

    const int q = q0 + l5;
    const float sc = q_mask[b * SS + q] / l_i;
    // O^T reg r: d = db*32 + (r&3) + 8*(r>>2) + 4*hi, col q = l5
    #pragma unroll
    for (int db = 0; db < 2; ++db) {
        const f32x16 oa = db ? o1 : o0;
        #pragma unroll
        for (int g = 0; g < 4; ++g) {
            f32x4 o4;
            o4[0] = oa[g * 4 + 0] * sc;
            o4[1] = oa[g * 4 + 1] * sc;
            o4[2] = oa[g * 4 + 2] * sc;
            o4[3] = oa[g * 4 + 3] * sc;
            *(f32x4*)&out[(size_t)(b * SS + q) * 1024 + h * 64 +
                          db * 32 + g * 8 + hi * 4] = o4;
        }
    }
}

// ---------------------------------------------------------------------------
extern "C" void kernel_launch(void* const* d_in, const int* in_sizes, int n_in,
                              void* d_out, int out_size, void* d_ws, size_t ws_size,
                              hipStream_t stream)
{
    const float* q  = (const float*)d_in[0];
    const float* k  = (const float*)d_in[1];
    const float* v  = (const float*)d_in[2];
    const float* vm = (const float*)d_in[3];
    const float* qm = (const float*)d_in[4];
    const float* Wq = (const float*)d_in[5];
    const float* Wk = (const float*)d_in[6];
    const float* Wv = (const float*)d_in[7];
    float* out = (float*)d_out;

    const size_t elems = (size_t)BB * SS * DD;  // 8388608
    bf16_t* Ab  = (bf16_t*)d_ws;       // qb,kb,vb: 3*elems
    bf16_t* qw  = Ab + 3 * elems;
    bf16_t* kw  = qw + elems;
    bf16_t* vwt = kw + elems;
    bf16_t* Wt  = vwt + elems;         // 3 x 1024 x 1024

    conv_kernel<<<dim3(4096, 1, 3), 256, 0, stream>>>(q, k, v, Ab);
    wtrans_kernel<<<dim3(16, 16, 3), 256, 0, stream>>>(Wq, Wk, Wv, Wt);
    proj_kernel<<<dim3(512, 1, 3), 256, 0, stream>>>(Ab, Wt, qw, kw, vwt);
    attn_kernel<<<dim3(1024, 1, 1), 256, 0, stream>>>(qw, kw, vwt, vm, qm, out);
}